// Round 7
// baseline (266.064 us; speedup 1.0000x reference)
//
#include <hip/hip_runtime.h>
#include <hip/hip_bf16.h>
#include <cmath>

#define S_LEN 2048
#define D_MODEL 2048
#define N_HEADS 16
#define Q_LORA 1536
#define KV_LORA 512
#define NOPE 128
#define ROPE_D 64
#define VD 128
#define QHD 192
#define AC_W 2112  // fused a-proj output width: 1536 q_a + 576 ckv

typedef __attribute__((ext_vector_type(8))) short bf16x8;
typedef __attribute__((ext_vector_type(4))) float f32x4;
typedef __attribute__((ext_vector_type(4))) unsigned short u16x4;

static __device__ __forceinline__ unsigned short f2u(float x) {
  union { float f; unsigned u; } v; v.f = x;
  unsigned r = v.u + 0x7fffu + ((v.u >> 16) & 1u);  // RNE
  return (unsigned short)(r >> 16);
}
static __device__ __forceinline__ unsigned short f2u_fast(float x) {  // round-half-up, x>=0
  union { float f; unsigned u; } v; v.f = x;
  return (unsigned short)((v.u + 0x8000u) >> 16);
}
static __device__ __forceinline__ float u2f(unsigned short x) {
  union { unsigned u; float f; } v; v.u = ((unsigned)x) << 16;
  return v.f;
}

#define AS1 __attribute__((address_space(1)))
#define AS3 __attribute__((address_space(3)))
static __device__ __forceinline__ void gload_lds16(const unsigned short* g, unsigned short* l) {
  __builtin_amdgcn_global_load_lds((const AS1 unsigned int*)g, (AS3 unsigned int*)l, 16, 0, 0);
}

// ---------------------------------------------------------------------------
// f32 -> bf16 convert (optionally scaled). n4 = elements/4.
// ---------------------------------------------------------------------------
__global__ __launch_bounds__(256) void conv_bf16(const float* __restrict__ src,
                                                 unsigned short* __restrict__ dst,
                                                 int n4, float scale) {
  for (int i = blockIdx.x * 256 + threadIdx.x; i < n4; i += gridDim.x * 256) {
    const float4 v = ((const float4*)src)[i];
    u16x4 o;
    o[0] = f2u(v.x * scale); o[1] = f2u(v.y * scale);
    o[2] = f2u(v.z * scale); o[3] = f2u(v.w * scale);
    ((u16x4*)dst)[i] = o;
  }
}

// two-segment variant (fused q_a_w + kv_a_w conversion)
__global__ __launch_bounds__(256) void conv2_bf16(const float* __restrict__ srcA, int n4a,
                                                  const float* __restrict__ srcB, int n4total,
                                                  unsigned short* __restrict__ dst) {
  for (int i = blockIdx.x * 256 + threadIdx.x; i < n4total; i += gridDim.x * 256) {
    const float4 v = (i < n4a) ? ((const float4*)srcA)[i] : ((const float4*)srcB)[i - n4a];
    u16x4 o;
    o[0] = f2u(v.x); o[1] = f2u(v.y); o[2] = f2u(v.z); o[3] = f2u(v.w);
    ((u16x4*)dst)[i] = o;
  }
}

// ---------------------------------------------------------------------------
// bf16 MFMA GEMM: C[M,N] = A[M,K] @ W[N,K]^T. 128x128 tile, BK=64, 4 waves,
// double-buffered LDS (64 KB), ONE barrier per 64-k step (half the intervals
// of the BK=32 version). 8-slot rows, slot ^ (row&7) XOR swizzle applied on
// the GLOBAL source at stage time (linear LDS dest for global_load_lds) and
// again on the ds_read side -> canonical data, conflict-free banks.
// MODE 0: f32 C. MODE 1: bf16 C. MODE 2: kv-split (k_nope->C2=Kb, V->Cv).
// ---------------------------------------------------------------------------
template <int MODE>
__global__ __launch_bounds__(256) void gemm_mfma(const unsigned short* __restrict__ A,
                                                 const unsigned short* __restrict__ W,
                                                 void* __restrict__ Cv,
                                                 unsigned short* __restrict__ C2,
                                                 int N, int K) {
  __shared__ unsigned short As[2][8192];  // 128 x 64 bf16
  __shared__ unsigned short Ws[2][8192];
  const int tid = threadIdx.x;
  const int wave = tid >> 6, lane = tid & 63;
  const int col16 = lane & 15, g = lane >> 4;
  const int arow = blockIdx.y * 128, wrow = blockIdx.x * 128;
  const int wm = (wave >> 1) * 64, wn = (wave & 1) * 64;

  // staging: 1024 chunks of 16B per matrix per buffer; thread handles 4.
  const unsigned short* gA[4];
  const unsigned short* gW[4];
  int dstOff[4];
#pragma unroll
  for (int i = 0; i < 4; ++i) {
    const int c = i * 256 + tid;
    const int r = c >> 3, sl = c & 7;
    const int ko = (sl ^ (r & 7)) * 8;
    gA[i] = A + (size_t)(arow + r) * K + ko;
    const int wr = (wrow + r < N) ? wrow + r : N - 1;
    gW[i] = W + (size_t)wr * K + ko;
    dstOff[i] = c * 8;
  }

  f32x4 acc[4][4];
#pragma unroll
  for (int i = 0; i < 4; ++i)
#pragma unroll
    for (int j = 0; j < 4; ++j) acc[i][j] = (f32x4){0.f, 0.f, 0.f, 0.f};

  // prologue: stage k=0 into buffer 0
#pragma unroll
  for (int i = 0; i < 4; ++i) {
    gload_lds16(gA[i], &As[0][dstOff[i]]);
    gload_lds16(gW[i], &Ws[0][dstOff[i]]);
  }

  int cur = 0;
  for (int k0 = 0; k0 < K; k0 += 64) {
    __syncthreads();  // buf[cur] staged; prior reads of buf[cur^1] drained
    if (k0 + 64 < K) {
      const int b = cur ^ 1, kk = k0 + 64;
#pragma unroll
      for (int i = 0; i < 4; ++i) {
        gload_lds16(gA[i] + kk, &As[b][dstOff[i]]);
        gload_lds16(gW[i] + kk, &Ws[b][dstOff[i]]);
      }
    }
#pragma unroll
    for (int kh = 0; kh < 2; ++kh) {
      bf16x8 af[4], bfr[4];
#pragma unroll
      for (int i = 0; i < 4; ++i) {
        const int row = wm + i * 16 + col16;
        af[i] = *(const bf16x8*)(&As[cur][row * 64 + (((kh * 4 + g) ^ (row & 7)) * 8)]);
      }
#pragma unroll
      for (int j = 0; j < 4; ++j) {
        const int row = wn + j * 16 + col16;
        bfr[j] = *(const bf16x8*)(&Ws[cur][row * 64 + (((kh * 4 + g) ^ (row & 7)) * 8)]);
      }
#pragma unroll
      for (int i = 0; i < 4; ++i)
#pragma unroll
        for (int j = 0; j < 4; ++j)
          acc[i][j] = __builtin_amdgcn_mfma_f32_16x16x32_bf16(af[i], bfr[j], acc[i][j], 0, 0, 0);
    }
    cur ^= 1;
  }

#pragma unroll
  for (int i = 0; i < 4; ++i)
#pragma unroll
    for (int j = 0; j < 4; ++j) {
      const int col = wrow + wn + j * 16 + col16;
      if (col < N) {
        const int row0 = arow + wm + i * 16 + g * 4;
#pragma unroll
        for (int r = 0; r < 4; ++r) {
          if constexpr (MODE == 0)
            ((float*)Cv)[(size_t)(row0 + r) * N + col] = acc[i][j][r];
          else if constexpr (MODE == 1)
            ((unsigned short*)Cv)[(size_t)(row0 + r) * N + col] = f2u(acc[i][j][r]);
          else {
            const int hh = col >> 8, d = col & 255;
            if (d < NOPE)
              C2[((size_t)hh * S_LEN + row0 + r) * QHD + d] = f2u(acc[i][j][r]);
            else
              ((unsigned short*)Cv)[(size_t)(row0 + r) * (N_HEADS * 256) + col] = f2u(acc[i][j][r]);
          }
        }
      }
    }
}

// ---------------------------------------------------------------------------
// RMSNorm over last dim, f32 in -> bf16 out.
// ---------------------------------------------------------------------------
__global__ __launch_bounds__(256) void rmsnorm_kernel(const float* __restrict__ src, int src_ld,
                                                      const float* __restrict__ w,
                                                      unsigned short* __restrict__ dst, int dst_ld,
                                                      int dim) {
  const int row = blockIdx.x;
  const float* x = src + (size_t)row * src_ld;
  float ss = 0.f;
  for (int i = threadIdx.x; i < dim; i += 256) {
    float v = x[i];
    ss += v * v;
  }
#pragma unroll
  for (int off = 32; off; off >>= 1) ss += __shfl_xor(ss, off);
  __shared__ float red[4];
  const int wv = threadIdx.x >> 6, ln = threadIdx.x & 63;
  if (ln == 0) red[wv] = ss;
  __syncthreads();
  const float tot = red[0] + red[1] + red[2] + red[3];
  const float scale = rsqrtf(tot / (float)dim + 1e-6f);
  for (int i = threadIdx.x; i < dim; i += 256) {
    dst[(size_t)row * dst_ld + i] = f2u(w[i] * (x[i] * scale));
  }
}

// ---------------------------------------------------------------------------
// RoPE: q_pe slices of bf16 qbuf in place; k_pe -> broadcast into Kb.
// ---------------------------------------------------------------------------
__global__ void rope_kernel(unsigned short* __restrict__ q, const float* __restrict__ ac,
                            unsigned short* __restrict__ Kb, const int* __restrict__ pos_ids) {
  const int s = blockIdx.x;
  const int j = threadIdx.x;  // 0..31
  const float t = (float)pos_ids[s];
  const float invf = powf(50000.0f, -(float)(2 * j) / 64.0f);
  const float ang = t * invf;
  const float c = cosf(ang), sn = sinf(ang);
  for (int h = 0; h < N_HEADS; ++h) {
    unsigned short* base = q + (size_t)s * (N_HEADS * QHD) + h * QHD + NOPE;
    const float x0 = u2f(base[2 * j]), x1 = u2f(base[2 * j + 1]);
    __syncthreads();
    base[j] = f2u(x0 * c - x1 * sn);
    base[32 + j] = f2u(x1 * c + x0 * sn);
    __syncthreads();
  }
  const float* kb = ac + (size_t)s * AC_W + 2048;
  const unsigned short r0 = f2u(kb[2 * j] * c - kb[2 * j + 1] * sn);
  const unsigned short r1 = f2u(kb[2 * j + 1] * c + kb[2 * j] * sn);
#pragma unroll
  for (int h = 0; h < N_HEADS; ++h) {
    unsigned short* kd = Kb + ((size_t)h * S_LEN + s) * QHD + NOPE;
    kd[j] = r0;
    kd[32 + j] = r1;
  }
}

// ---------------------------------------------------------------------------
// V transpose + PERMUTED column order (PV fragment order), unchanged.
// ---------------------------------------------------------------------------
__global__ __launch_bounds__(256) void build_vt(const unsigned short* __restrict__ kv,
                                                unsigned short* __restrict__ Vt) {
  __shared__ unsigned short t[32][33];
  const int s0 = blockIdx.x * 32, d0 = blockIdx.y * 32, h = blockIdx.z;
  const int tx = threadIdx.x & 31, ty = threadIdx.x >> 5;
#pragma unroll
  for (int i = 0; i < 4; ++i) {
    const int s = s0 + ty + i * 8;
    t[ty + i * 8][tx] = kv[(size_t)s * (N_HEADS * 256) + h * 256 + NOPE + d0 + tx];
  }
  __syncthreads();
  const int p = ((tx & 15) >> 2) * 8 + ((tx >> 4) & 1) * 4 + (tx & 3);
#pragma unroll
  for (int i = 0; i < 4; ++i) {
    const int d = d0 + ty + i * 8;
    Vt[((size_t)h * VD + d) * S_LEN + s0 + p] = t[tx][ty + i * 8];
  }
}

// ---------------------------------------------------------------------------
// MFMA flash attention, 32 q-cols per wave (each K/V ds_read feeds TWO MFMAs
// -> LDS bytes per FLOP halved vs 16-q waves; kernel was LDS-BW-bound).
// Blocks: 128 threads = 2 waves x 32 q = 64 rows; grid 512; LDS 80 KB
// double-buffered 64-k K/V tiles (2 blocks/CU = 160 KB exactly).
// Same proven XOR swizzles (pre-swizzled global src + same XOR on ds_read).
// exp2-domain softmax, defer-max THR=8, diagonal-only masking, balanced
// (qtile,h) pairing, XCD head-pair locality.
// ---------------------------------------------------------------------------
__global__ __launch_bounds__(128) void flash_attn(const unsigned short* __restrict__ Q,   // (S,3072) pre-scaled
                                                  const unsigned short* __restrict__ Kb,  // (H,S,192)
                                                  const unsigned short* __restrict__ Vt,  // (H,128,S) permuted
                                                  unsigned short* __restrict__ out) {     // (S,2048)
  __shared__ unsigned short Ks[2][64 * QHD];   // 2 x 24 KB
  __shared__ unsigned short Vs[2][VD * 64];    // 2 x 16 KB
  const int tid = threadIdx.x;                 // 0..127
  const int wave = tid >> 6, lane = tid & 63;
  const int g = lane >> 4, col = lane & 15;
  const int lin = (int)blockIdx.x + ((int)blockIdx.y << 5);
  const int h = ((lin & 7) << 1) | ((lin >> 3) & 1);
  const int z = lin >> 4;                                // 0..31
  const int qtile = (z < 16) ? (31 - z) : (z - 16);      // balanced pairing
  const int qwv = qtile * 64 + wave * 32;
  const int qrA = qwv + col, qrB = qwv + 16 + col;

  bf16x8 qfA[6], qfB[6];
  {
    const unsigned short* qa = Q + (size_t)qrA * (N_HEADS * QHD) + h * QHD + g * 8;
    const unsigned short* qb = Q + (size_t)qrB * (N_HEADS * QHD) + h * QHD + g * 8;
#pragma unroll
    for (int t = 0; t < 6; ++t) {
      qfA[t] = *(const bf16x8*)(qa + t * 32);
      qfB[t] = *(const bf16x8*)(qb + t * 32);
    }
  }

  const unsigned short* KbH = Kb + (size_t)h * S_LEN * QHD;
  const unsigned short* VtH = Vt + (size_t)h * VD * S_LEN;

  // staging source offsets (pre-swizzled slots; fixed across tiles)
  int eK[12], eV[8];
#pragma unroll
  for (int i = 0; i < 12; ++i) {               // 1536 K chunks of 16B
    const int c = i * 128 + tid;
    const int r = c / 24, sl = c - r * 24;
    eK[i] = r * QHD + (((sl & 24) | ((sl & 7) ^ (r & 7)))) * 8;
  }
#pragma unroll
  for (int i = 0; i < 8; ++i) {                // 1024 V chunks of 16B
    const int c = i * 128 + tid;
    const int d = c >> 3, sl = c & 7;
    eV[i] = d * S_LEN + ((sl ^ (d & 7))) * 8;
  }

  f32x4 oA[8], oB[8];
#pragma unroll
  for (int i = 0; i < 8; ++i) {
    oA[i] = (f32x4){0.f, 0.f, 0.f, 0.f};
    oB[i] = (f32x4){0.f, 0.f, 0.f, 0.f};
  }
  float mA = -1e30f, lA = 0.f, mB = -1e30f, lB = 0.f;

  const int nT = qtile + 1;

  // prologue: stage tile 0 into buffer 0
#pragma unroll
  for (int i = 0; i < 12; ++i) gload_lds16(KbH + eK[i], &Ks[0][(i * 128 + tid) * 8]);
#pragma unroll
  for (int i = 0; i < 8; ++i) gload_lds16(VtH + eV[i], &Vs[0][(i * 128 + tid) * 8]);

  int xK[6];
#pragma unroll
  for (int t = 0; t < 6; ++t) xK[t] = ((4 * t + g) ^ (col & 7)) * 8;
  const int rbK = col * QHD;
  const int rbV = col * 64;

  for (int tt = 0; tt < nT; ++tt) {
    __syncthreads();
    if (tt + 1 < nT) {
      const unsigned short* kp = KbH + (size_t)(tt + 1) * 64 * QHD;
      const unsigned short* vp = VtH + (tt + 1) * 64;
      const int b = (tt + 1) & 1;
#pragma unroll
      for (int i = 0; i < 12; ++i) gload_lds16(kp + eK[i], &Ks[b][(i * 128 + tid) * 8]);
#pragma unroll
      for (int i = 0; i < 8; ++i) gload_lds16(vp + eV[i], &Vs[b][(i * 128 + tid) * 8]);
    }
    const unsigned short* Ksc = Ks[tt & 1];
    const unsigned short* Vsc = Vs[tt & 1];
    const int k0 = tt * 64;

    f32x4 cA[4], cB[4];
#pragma unroll
    for (int f = 0; f < 4; ++f) {
      cA[f] = (f32x4){0.f, 0.f, 0.f, 0.f};
      cB[f] = (f32x4){0.f, 0.f, 0.f, 0.f};
    }
    __builtin_amdgcn_s_setprio(1);
#pragma unroll
    for (int dt = 0; dt < 6; ++dt) {
#pragma unroll
      for (int f = 0; f < 4; ++f) {
        const bf16x8 a = *(const bf16x8*)(Ksc + rbK + f * 16 * QHD + xK[dt]);
        cA[f] = __builtin_amdgcn_mfma_f32_16x16x32_bf16(a, qfA[dt], cA[f], 0, 0, 0);
        cB[f] = __builtin_amdgcn_mfma_f32_16x16x32_bf16(a, qfB[dt], cB[f], 0, 0, 0);
      }
    }
    __builtin_amdgcn_s_setprio(0);

    // masks only on diagonal tiles (k = k0 + 16f + 4g + r; q = qrA/qrB)
    if (k0 + 63 > qwv) {
#pragma unroll
      for (int f = 0; f < 4; ++f)
#pragma unroll
        for (int r = 0; r < 4; ++r) {
          const int kk = k0 + 16 * f + 4 * g + r;
          if (kk > qrA) cA[f][r] = -1e30f;
          if (kk > qrB) cB[f][r] = -1e30f;
        }
    }
    // group A softmax
    {
      float bm = cA[0][0];
#pragma unroll
      for (int f = 0; f < 4; ++f)
#pragma unroll
        for (int r = 0; r < 4; ++r) bm = fmaxf(bm, cA[f][r]);
      bm = fmaxf(bm, __shfl_xor(bm, 16));
      bm = fmaxf(bm, __shfl_xor(bm, 32));
      const bool skip = __all(bm <= mA + 8.f);
      const float mn = skip ? mA : fmaxf(mA, bm);
      float ps = 0.f;
      bf16x8 pb0, pb1;
#pragma unroll
      for (int f = 0; f < 4; ++f)
#pragma unroll
        for (int r = 0; r < 4; ++r) {
          const float p = exp2f(cA[f][r] - mn);
          ps += p;
          if (f < 2) pb0[(f & 1) * 4 + r] = (short)f2u_fast(p);
          else       pb1[(f & 1) * 4 + r] = (short)f2u_fast(p);
        }
      ps += __shfl_xor(ps, 16);
      ps += __shfl_xor(ps, 32);
      if (skip) {
        lA += ps;
      } else {
        const float corr = exp2f(mA - mn);
        lA = lA * corr + ps;
        mA = mn;
#pragma unroll
        for (int i = 0; i < 8; ++i) {
          oA[i][0] *= corr; oA[i][1] *= corr; oA[i][2] *= corr; oA[i][3] *= corr;
        }
      }
      __builtin_amdgcn_s_setprio(1);
#pragma unroll
      for (int db = 0; db < 8; ++db) {
        const bf16x8 va0 = *(const bf16x8*)(Vsc + db * 1024 + rbV + xK[0]);
        oA[db] = __builtin_amdgcn_mfma_f32_16x16x32_bf16(va0, pb0, oA[db], 0, 0, 0);
        const bf16x8 va1 = *(const bf16x8*)(Vsc + db * 1024 + rbV + xK[1]);
        oA[db] = __builtin_amdgcn_mfma_f32_16x16x32_bf16(va1, pb1, oA[db], 0, 0, 0);
      }
      __builtin_amdgcn_s_setprio(0);
    }
    // group B softmax
    {
      float bm = cB[0][0];
#pragma unroll
      for (int f = 0; f < 4; ++f)
#pragma unroll
        for (int r = 0; r < 4; ++r) bm = fmaxf(bm, cB[f][r]);
      bm = fmaxf(bm, __shfl_xor(bm, 16));
      bm = fmaxf(bm, __shfl_xor(bm, 32));
      const bool skip = __all(bm <= mB + 8.f);
      const float mn = skip ? mB : fmaxf(mB, bm);
      float ps = 0.f;
      bf16x8 pb0, pb1;
#pragma unroll
      for (int f = 0; f < 4; ++f)
#pragma unroll
        for (int r = 0; r < 4; ++r) {
          const float p = exp2f(cB[f][r] - mn);
          ps += p;
          if (f < 2) pb0[(f & 1) * 4 + r] = (short)f2u_fast(p);
          else       pb1[(f & 1) * 4 + r] = (short)f2u_fast(p);
        }
      ps += __shfl_xor(ps, 16);
      ps += __shfl_xor(ps, 32);
      if (skip) {
        lB += ps;
      } else {
        const float corr = exp2f(mB - mn);
        lB = lB * corr + ps;
        mB = mn;
#pragma unroll
        for (int i = 0; i < 8; ++i) {
          oB[i][0] *= corr; oB[i][1] *= corr; oB[i][2] *= corr; oB[i][3] *= corr;
        }
      }
      __builtin_amdgcn_s_setprio(1);
#pragma unroll
      for (int db = 0; db < 8; ++db) {
        const bf16x8 va0 = *(const bf16x8*)(Vsc + db * 1024 + rbV + xK[0]);
        oB[db] = __builtin_amdgcn_mfma_f32_16x16x32_bf16(va0, pb0, oB[db], 0, 0, 0);
        const bf16x8 va1 = *(const bf16x8*)(Vsc + db * 1024 + rbV + xK[1]);
        oB[db] = __builtin_amdgcn_mfma_f32_16x16x32_bf16(va1, pb1, oB[db], 0, 0, 0);
      }
      __builtin_amdgcn_s_setprio(0);
    }
  }

  const float invA = 1.f / lA, invB = 1.f / lB;
  unsigned short* orA = out + (size_t)qrA * (N_HEADS * VD) + h * VD;
  unsigned short* orB = out + (size_t)qrB * (N_HEADS * VD) + h * VD;
#pragma unroll
  for (int db = 0; db < 8; ++db)
#pragma unroll
    for (int r = 0; r < 4; ++r) {
      orA[db * 16 + 4 * g + r] = f2u(oA[db][r] * invA);
      orB[db * 16 + 4 * g + r] = f2u(oB[db][r] * invB);
    }
}

// ---------------------------------------------------------------------------
extern "C" void kernel_launch(void* const* d_in, const int* in_sizes, int n_in,
                              void* d_out, int out_size, void* d_ws, size_t ws_size,
                              hipStream_t stream) {
  const float* hidden    = (const float*)d_in[0];
  const int*   pos       = (const int*)d_in[1];
  const float* q_a_w     = (const float*)d_in[2];
  const float* q_a_ln_w  = (const float*)d_in[3];
  const float* q_b_w     = (const float*)d_in[4];
  const float* kv_a_w    = (const float*)d_in[5];
  const float* kv_a_ln_w = (const float*)d_in[6];
  const float* kv_b_w    = (const float*)d_in[7];
  const float* o_w       = (const float*)d_in[8];
  float* out = (float*)d_out;
  (void)in_sizes; (void)n_in; (void)out_size; (void)ws_size;

  // workspace layout (bytes); total ~94 MB
  char* base = (char*)d_ws;
  unsigned short* qbuf  = (unsigned short*)(base);              // S*3072 bf16  12.58MB
  unsigned short* kvbuf = (unsigned short*)(base + 12582912);   // S*4096 bf16  16.78MB (V half only)
  float*          ac    = (float*)(base + 29360128);            // S*2112 f32   17.30MB
  unsigned short* qan   = (unsigned short*)(base + 46661632);   // S*1536 bf16   6.29MB
  unsigned short* ckvn  = (unsigned short*)(base + 52953088);   // S*512 bf16    2.10MB
  unsigned short* Hb    = (unsigned short*)(base + 55050240);   // S*2048 bf16   8.39MB
  unsigned short* Vt    = (unsigned short*)(base + 55050240);   //   overlay (Hb dead after a-proj)
  unsigned short* wbuf  = (unsigned short*)(base + 63438848);   // 4.72M bf16    9.44MB
  unsigned short* attnb = (unsigned short*)(base + 72876032);   // S*2048 bf16   8.39MB
  unsigned short* Kb    = (unsigned short*)(base + 81264640);   // 16*S*192 bf16 12.58MB

  const dim3 b256(256);
  // 192^-0.5 * log2(e): scores come out of QK^T directly in log2 domain
  const float qscale = 0.07216878364870323f * 1.4426950408889634f;

  conv_bf16<<<2048, b256, 0, stream>>>(hidden, Hb, (S_LEN * D_MODEL) / 4, 1.f);

  // fused a-proj: W = [q_a_w ; kv_a_w] (2112 x 2048), C = ac f32 (S x 2112)
  conv2_bf16<<<2048, b256, 0, stream>>>(q_a_w, (Q_LORA * D_MODEL) / 4,
                                        kv_a_w, (AC_W * D_MODEL) / 4, wbuf);
  gemm_mfma<0><<<dim3(17, S_LEN / 128), b256, 0, stream>>>(Hb, wbuf, ac, nullptr, AC_W, D_MODEL);

  rmsnorm_kernel<<<S_LEN, b256, 0, stream>>>(ac, AC_W, q_a_ln_w, qan, Q_LORA, Q_LORA);
  rmsnorm_kernel<<<S_LEN, b256, 0, stream>>>(ac + Q_LORA, AC_W, kv_a_ln_w, ckvn, KV_LORA, KV_LORA);

  // qbuf = qan @ (qscale*q_b_w)^T   (bf16 out)
  conv_bf16<<<2048, b256, 0, stream>>>(q_b_w, wbuf, (N_HEADS * QHD * Q_LORA) / 4, qscale);
  gemm_mfma<1><<<dim3(N_HEADS * QHD / 128, S_LEN / 128), b256, 0, stream>>>(qan, wbuf, qbuf, nullptr, N_HEADS * QHD, Q_LORA);

  // kv_b: k_nope -> Kb directly, values -> kvbuf
  conv_bf16<<<2048, b256, 0, stream>>>(kv_b_w, wbuf, (N_HEADS * 256 * KV_LORA) / 4, 1.f);
  gemm_mfma<2><<<dim3(N_HEADS * 256 / 128, S_LEN / 128), b256, 0, stream>>>(ckvn, wbuf, kvbuf, Kb, N_HEADS * 256, KV_LORA);

  // rope: qbuf q_pe in place; k_pe -> Kb cols 128..192 (all heads)
  rope_kernel<<<S_LEN, 32, 0, stream>>>(qbuf, ac, Kb, pos);

  build_vt<<<dim3(S_LEN / 32, VD / 32, N_HEADS), b256, 0, stream>>>(kvbuf, Vt);
  flash_attn<<<dim3(32, 16), dim3(128), 0, stream>>>(qbuf, Kb, Vt, attnb);

  conv_bf16<<<2048, b256, 0, stream>>>(o_w, wbuf, (D_MODEL * N_HEADS * VD) / 4, 1.f);
  gemm_mfma<0><<<dim3(D_MODEL / 128, S_LEN / 128), b256, 0, stream>>>(attnb, wbuf, out, nullptr, D_MODEL, N_HEADS * VD);
}

// Round 8
// 250.436 us; speedup vs baseline: 1.0624x; 1.0624x over previous
//
#include <hip/hip_runtime.h>
#include <hip/hip_bf16.h>
#include <cmath>

#define S_LEN 2048
#define D_MODEL 2048
#define N_HEADS 16
#define Q_LORA 1536
#define KV_LORA 512
#define NOPE 128
#define ROPE_D 64
#define VD 128
#define QHD 192
#define AC_W 2112  // fused a-proj output width: 1536 q_a + 576 ckv

typedef __attribute__((ext_vector_type(8))) short bf16x8;
typedef __attribute__((ext_vector_type(4))) float f32x4;
typedef __attribute__((ext_vector_type(4))) unsigned short u16x4;

static __device__ __forceinline__ unsigned short f2u(float x) {
  union { float f; unsigned u; } v; v.f = x;
  unsigned r = v.u + 0x7fffu + ((v.u >> 16) & 1u);  // RNE
  return (unsigned short)(r >> 16);
}
static __device__ __forceinline__ unsigned short f2u_fast(float x) {  // round-half-up, x>=0
  union { float f; unsigned u; } v; v.f = x;
  return (unsigned short)((v.u + 0x8000u) >> 16);
}
static __device__ __forceinline__ float u2f(unsigned short x) {
  union { unsigned u; float f; } v; v.u = ((unsigned)x) << 16;
  return v.f;
}

#define AS1 __attribute__((address_space(1)))
#define AS3 __attribute__((address_space(3)))
static __device__ __forceinline__ void gload_lds16(const unsigned short* g, unsigned short* l) {
  __builtin_amdgcn_global_load_lds((const AS1 unsigned int*)g, (AS3 unsigned int*)l, 16, 0, 0);
}

// ---------------------------------------------------------------------------
// f32 -> bf16 convert (optionally scaled). n4 = elements/4.
// ---------------------------------------------------------------------------
__global__ __launch_bounds__(256) void conv_bf16(const float* __restrict__ src,
                                                 unsigned short* __restrict__ dst,
                                                 int n4, float scale) {
  for (int i = blockIdx.x * 256 + threadIdx.x; i < n4; i += gridDim.x * 256) {
    const float4 v = ((const float4*)src)[i];
    u16x4 o;
    o[0] = f2u(v.x * scale); o[1] = f2u(v.y * scale);
    o[2] = f2u(v.z * scale); o[3] = f2u(v.w * scale);
    ((u16x4*)dst)[i] = o;
  }
}

// two-segment variant (fused q_a_w + kv_a_w conversion)
__global__ __launch_bounds__(256) void conv2_bf16(const float* __restrict__ srcA, int n4a,
                                                  const float* __restrict__ srcB, int n4total,
                                                  unsigned short* __restrict__ dst) {
  for (int i = blockIdx.x * 256 + threadIdx.x; i < n4total; i += gridDim.x * 256) {
    const float4 v = (i < n4a) ? ((const float4*)srcA)[i] : ((const float4*)srcB)[i - n4a];
    u16x4 o;
    o[0] = f2u(v.x); o[1] = f2u(v.y); o[2] = f2u(v.z); o[3] = f2u(v.w);
    ((u16x4*)dst)[i] = o;
  }
}

// ---------------------------------------------------------------------------
// bf16 MFMA GEMM: C[M,N] = A[M,K] @ W[N,K]^T. 128x128 tile, BK=64, 4 waves,
// double-buffered LDS, one barrier per 64-k step. (unchanged from round 7)
// ---------------------------------------------------------------------------
template <int MODE>
__global__ __launch_bounds__(256) void gemm_mfma(const unsigned short* __restrict__ A,
                                                 const unsigned short* __restrict__ W,
                                                 void* __restrict__ Cv,
                                                 unsigned short* __restrict__ C2,
                                                 int N, int K) {
  __shared__ unsigned short As[2][8192];  // 128 x 64 bf16
  __shared__ unsigned short Ws[2][8192];
  const int tid = threadIdx.x;
  const int wave = tid >> 6, lane = tid & 63;
  const int col16 = lane & 15, g = lane >> 4;
  const int arow = blockIdx.y * 128, wrow = blockIdx.x * 128;
  const int wm = (wave >> 1) * 64, wn = (wave & 1) * 64;

  const unsigned short* gA[4];
  const unsigned short* gW[4];
  int dstOff[4];
#pragma unroll
  for (int i = 0; i < 4; ++i) {
    const int c = i * 256 + tid;
    const int r = c >> 3, sl = c & 7;
    const int ko = (sl ^ (r & 7)) * 8;
    gA[i] = A + (size_t)(arow + r) * K + ko;
    const int wr = (wrow + r < N) ? wrow + r : N - 1;
    gW[i] = W + (size_t)wr * K + ko;
    dstOff[i] = c * 8;
  }

  f32x4 acc[4][4];
#pragma unroll
  for (int i = 0; i < 4; ++i)
#pragma unroll
    for (int j = 0; j < 4; ++j) acc[i][j] = (f32x4){0.f, 0.f, 0.f, 0.f};

#pragma unroll
  for (int i = 0; i < 4; ++i) {
    gload_lds16(gA[i], &As[0][dstOff[i]]);
    gload_lds16(gW[i], &Ws[0][dstOff[i]]);
  }

  int cur = 0;
  for (int k0 = 0; k0 < K; k0 += 64) {
    __syncthreads();
    if (k0 + 64 < K) {
      const int b = cur ^ 1, kk = k0 + 64;
#pragma unroll
      for (int i = 0; i < 4; ++i) {
        gload_lds16(gA[i] + kk, &As[b][dstOff[i]]);
        gload_lds16(gW[i] + kk, &Ws[b][dstOff[i]]);
      }
    }
#pragma unroll
    for (int kh = 0; kh < 2; ++kh) {
      bf16x8 af[4], bfr[4];
#pragma unroll
      for (int i = 0; i < 4; ++i) {
        const int row = wm + i * 16 + col16;
        af[i] = *(const bf16x8*)(&As[cur][row * 64 + (((kh * 4 + g) ^ (row & 7)) * 8)]);
      }
#pragma unroll
      for (int j = 0; j < 4; ++j) {
        const int row = wn + j * 16 + col16;
        bfr[j] = *(const bf16x8*)(&Ws[cur][row * 64 + (((kh * 4 + g) ^ (row & 7)) * 8)]);
      }
#pragma unroll
      for (int i = 0; i < 4; ++i)
#pragma unroll
        for (int j = 0; j < 4; ++j)
          acc[i][j] = __builtin_amdgcn_mfma_f32_16x16x32_bf16(af[i], bfr[j], acc[i][j], 0, 0, 0);
    }
    cur ^= 1;
  }

#pragma unroll
  for (int i = 0; i < 4; ++i)
#pragma unroll
    for (int j = 0; j < 4; ++j) {
      const int col = wrow + wn + j * 16 + col16;
      if (col < N) {
        const int row0 = arow + wm + i * 16 + g * 4;
#pragma unroll
        for (int r = 0; r < 4; ++r) {
          if constexpr (MODE == 0)
            ((float*)Cv)[(size_t)(row0 + r) * N + col] = acc[i][j][r];
          else if constexpr (MODE == 1)
            ((unsigned short*)Cv)[(size_t)(row0 + r) * N + col] = f2u(acc[i][j][r]);
          else {
            const int hh = col >> 8, d = col & 255;
            if (d < NOPE)
              C2[((size_t)hh * S_LEN + row0 + r) * QHD + d] = f2u(acc[i][j][r]);
            else
              ((unsigned short*)Cv)[(size_t)(row0 + r) * (N_HEADS * 256) + col] = f2u(acc[i][j][r]);
          }
        }
      }
    }
}

// ---------------------------------------------------------------------------
// RMSNorm over last dim, f32 in -> bf16 out.
// ---------------------------------------------------------------------------
__global__ __launch_bounds__(256) void rmsnorm_kernel(const float* __restrict__ src, int src_ld,
                                                      const float* __restrict__ w,
                                                      unsigned short* __restrict__ dst, int dst_ld,
                                                      int dim) {
  const int row = blockIdx.x;
  const float* x = src + (size_t)row * src_ld;
  float ss = 0.f;
  for (int i = threadIdx.x; i < dim; i += 256) {
    float v = x[i];
    ss += v * v;
  }
#pragma unroll
  for (int off = 32; off; off >>= 1) ss += __shfl_xor(ss, off);
  __shared__ float red[4];
  const int wv = threadIdx.x >> 6, ln = threadIdx.x & 63;
  if (ln == 0) red[wv] = ss;
  __syncthreads();
  const float tot = red[0] + red[1] + red[2] + red[3];
  const float scale = rsqrtf(tot / (float)dim + 1e-6f);
  for (int i = threadIdx.x; i < dim; i += 256) {
    dst[(size_t)row * dst_ld + i] = f2u(w[i] * (x[i] * scale));
  }
}

// ---------------------------------------------------------------------------
// RoPE: q_pe slices of bf16 qbuf in place; k_pe -> broadcast into Kb.
// ---------------------------------------------------------------------------
__global__ void rope_kernel(unsigned short* __restrict__ q, const float* __restrict__ ac,
                            unsigned short* __restrict__ Kb, const int* __restrict__ pos_ids) {
  const int s = blockIdx.x;
  const int j = threadIdx.x;  // 0..31
  const float t = (float)pos_ids[s];
  const float invf = powf(50000.0f, -(float)(2 * j) / 64.0f);
  const float ang = t * invf;
  const float c = cosf(ang), sn = sinf(ang);
  for (int h = 0; h < N_HEADS; ++h) {
    unsigned short* base = q + (size_t)s * (N_HEADS * QHD) + h * QHD + NOPE;
    const float x0 = u2f(base[2 * j]), x1 = u2f(base[2 * j + 1]);
    __syncthreads();
    base[j] = f2u(x0 * c - x1 * sn);
    base[32 + j] = f2u(x1 * c + x0 * sn);
    __syncthreads();
  }
  const float* kb = ac + (size_t)s * AC_W + 2048;
  const unsigned short r0 = f2u(kb[2 * j] * c - kb[2 * j + 1] * sn);
  const unsigned short r1 = f2u(kb[2 * j + 1] * c + kb[2 * j] * sn);
#pragma unroll
  for (int h = 0; h < N_HEADS; ++h) {
    unsigned short* kd = Kb + ((size_t)h * S_LEN + s) * QHD + NOPE;
    kd[j] = r0;
    kd[32 + j] = r1;
  }
}

// ---------------------------------------------------------------------------
// V transpose + PERMUTED column order (PV fragment order), unchanged.
// ---------------------------------------------------------------------------
__global__ __launch_bounds__(256) void build_vt(const unsigned short* __restrict__ kv,
                                                unsigned short* __restrict__ Vt) {
  __shared__ unsigned short t[32][33];
  const int s0 = blockIdx.x * 32, d0 = blockIdx.y * 32, h = blockIdx.z;
  const int tx = threadIdx.x & 31, ty = threadIdx.x >> 5;
#pragma unroll
  for (int i = 0; i < 4; ++i) {
    const int s = s0 + ty + i * 8;
    t[ty + i * 8][tx] = kv[(size_t)s * (N_HEADS * 256) + h * 256 + NOPE + d0 + tx];
  }
  __syncthreads();
  const int p = ((tx & 15) >> 2) * 8 + ((tx >> 4) & 1) * 4 + (tx & 3);
#pragma unroll
  for (int i = 0; i < 4; ++i) {
    const int d = d0 + ty + i * 8;
    Vt[((size_t)h * VD + d) * S_LEN + s0 + p] = t[tx][ty + i * 8];
  }
}

// ---------------------------------------------------------------------------
// Split-K MFMA flash attention. Block = 256 thr = 4 waves x 32 q = 128 rows;
// split s processes k-tiles j == s (mod 2) (interleaved -> causally balanced).
// Grid 512 (16 qtiles x 16 heads x 2 splits) -> 2 blocks/CU (80 KB LDS),
// 2 waves/SIMD; per-CU intervals 17 (vs 33 in round 6); each K/V ds_read_b128
// feeds TWO MFMAs. Writes unnormalized f32 partials + (m,l); combine merges.
// Same proven XOR swizzles; exp2-domain softmax; defer-max THR=8;
// diagonal-only masking; (lin, lin+256) CU pairs sum to 17 intervals.
// ---------------------------------------------------------------------------
__global__ __launch_bounds__(256) void flash_attn(const unsigned short* __restrict__ Q,   // (S,3072) pre-scaled
                                                  const unsigned short* __restrict__ Kb,  // (H,S,192)
                                                  const unsigned short* __restrict__ Vt,  // (H,128,S) permuted
                                                  float* __restrict__ O0,                 // (S,2048) f32 partial s=0
                                                  float* __restrict__ O1,                 // (S,2048) f32 partial s=1
                                                  float2* __restrict__ ml0,               // (S,16) {m,l} s=0
                                                  float2* __restrict__ ml1) {             // (S,16) {m,l} s=1
  __shared__ unsigned short Ks[2][64 * QHD];   // 2 x 24 KB
  __shared__ unsigned short Vs[2][VD * 64];    // 2 x 16 KB
  const int tid = threadIdx.x;
  const int wave = tid >> 6, lane = tid & 63;
  const int g = lane >> 4, col = lane & 15;
  const int lin = (int)blockIdx.x;                 // 0..511
  const int h = ((lin & 7) << 1) | ((lin >> 3) & 1);  // XCD owns a head pair
  const int s = (lin >> 4) & 1;                    // k-split
  const int z = lin >> 5;                          // 0..15
  const int t = (z < 8) ? (15 - z) : (z - 8);      // pair (lin,lin+256): 17 intervals
  const int qwv = t * 128 + wave * 32;
  const int qrA = qwv + col, qrB = qwv + 16 + col;

  bf16x8 qfA[6], qfB[6];
  {
    const unsigned short* qa = Q + (size_t)qrA * (N_HEADS * QHD) + h * QHD + g * 8;
    const unsigned short* qb = Q + (size_t)qrB * (N_HEADS * QHD) + h * QHD + g * 8;
#pragma unroll
    for (int i = 0; i < 6; ++i) {
      qfA[i] = *(const bf16x8*)(qa + i * 32);
      qfB[i] = *(const bf16x8*)(qb + i * 32);
    }
  }

  const unsigned short* KbH = Kb + (size_t)h * S_LEN * QHD;
  const unsigned short* VtH = Vt + (size_t)h * VD * S_LEN;

  // staging source offsets (pre-swizzled slots; fixed across tiles)
  int eK[6], eV[4];
#pragma unroll
  for (int i = 0; i < 6; ++i) {                 // 1536 K chunks of 16B
    const int c = i * 256 + tid;
    const int r = c / 24, sl = c - r * 24;
    eK[i] = r * QHD + (((sl & 24) | ((sl & 7) ^ (r & 7)))) * 8;
  }
#pragma unroll
  for (int i = 0; i < 4; ++i) {                 // 1024 V chunks of 16B
    const int c = i * 256 + tid;
    const int d = c >> 3, sl = c & 7;
    eV[i] = d * S_LEN + ((sl ^ (d & 7))) * 8;
  }

  f32x4 oA[8], oB[8];
#pragma unroll
  for (int i = 0; i < 8; ++i) {
    oA[i] = (f32x4){0.f, 0.f, 0.f, 0.f};
    oB[i] = (f32x4){0.f, 0.f, 0.f, 0.f};
  }
  float mA = -1e30f, lA = 0.f, mB = -1e30f, lB = 0.f;

  const int nT = t + 1;  // tiles j = 2*it + s, it in [0,nT)

  // prologue: stage tile j=s into buffer 0
  {
    const unsigned short* kp = KbH + (size_t)s * 64 * QHD;
    const unsigned short* vp = VtH + s * 64;
#pragma unroll
    for (int i = 0; i < 6; ++i) gload_lds16(kp + eK[i], &Ks[0][(i * 256 + tid) * 8]);
#pragma unroll
    for (int i = 0; i < 4; ++i) gload_lds16(vp + eV[i], &Vs[0][(i * 256 + tid) * 8]);
  }

  int xK[6];
#pragma unroll
  for (int i = 0; i < 6; ++i) xK[i] = ((4 * i + g) ^ (col & 7)) * 8;
  const int rbK = col * QHD;
  const int rbV = col * 64;

  for (int it = 0; it < nT; ++it) {
    __syncthreads();
    if (it + 1 < nT) {
      const int jn = 2 * (it + 1) + s;
      const unsigned short* kp = KbH + (size_t)jn * 64 * QHD;
      const unsigned short* vp = VtH + jn * 64;
      const int b = (it + 1) & 1;
#pragma unroll
      for (int i = 0; i < 6; ++i) gload_lds16(kp + eK[i], &Ks[b][(i * 256 + tid) * 8]);
#pragma unroll
      for (int i = 0; i < 4; ++i) gload_lds16(vp + eV[i], &Vs[b][(i * 256 + tid) * 8]);
    }
    const int k0 = 64 * (2 * it + s);
    if (k0 <= qwv + 31) {
      const unsigned short* Ksc = Ks[it & 1];
      const unsigned short* Vsc = Vs[it & 1];

      f32x4 cA[4], cB[4];
#pragma unroll
      for (int f = 0; f < 4; ++f) {
        cA[f] = (f32x4){0.f, 0.f, 0.f, 0.f};
        cB[f] = (f32x4){0.f, 0.f, 0.f, 0.f};
      }
      __builtin_amdgcn_s_setprio(1);
#pragma unroll
      for (int dt = 0; dt < 6; ++dt) {
#pragma unroll
        for (int f = 0; f < 4; ++f) {
          const bf16x8 a = *(const bf16x8*)(Ksc + rbK + f * 16 * QHD + xK[dt]);
          cA[f] = __builtin_amdgcn_mfma_f32_16x16x32_bf16(a, qfA[dt], cA[f], 0, 0, 0);
          cB[f] = __builtin_amdgcn_mfma_f32_16x16x32_bf16(a, qfB[dt], cB[f], 0, 0, 0);
        }
      }
      __builtin_amdgcn_s_setprio(0);

      // masks only on diagonal tiles (k = k0 + 16f + 4g + r)
      if (k0 + 63 > qwv) {
#pragma unroll
        for (int f = 0; f < 4; ++f)
#pragma unroll
          for (int r = 0; r < 4; ++r) {
            const int kk = k0 + 16 * f + 4 * g + r;
            if (kk > qrA) cA[f][r] = -1e30f;
            if (kk > qrB) cB[f][r] = -1e30f;
          }
      }
      // softmax A
      bf16x8 pbA0, pbA1, pbB0, pbB1;
      {
        float bm = cA[0][0];
#pragma unroll
        for (int f = 0; f < 4; ++f)
#pragma unroll
          for (int r = 0; r < 4; ++r) bm = fmaxf(bm, cA[f][r]);
        bm = fmaxf(bm, __shfl_xor(bm, 16));
        bm = fmaxf(bm, __shfl_xor(bm, 32));
        const bool skip = __all(bm <= mA + 8.f);
        const float mn = skip ? mA : fmaxf(mA, bm);
        float ps = 0.f;
#pragma unroll
        for (int f = 0; f < 4; ++f)
#pragma unroll
          for (int r = 0; r < 4; ++r) {
            const float p = exp2f(cA[f][r] - mn);
            ps += p;
            if (f < 2) pbA0[(f & 1) * 4 + r] = (short)f2u_fast(p);
            else       pbA1[(f & 1) * 4 + r] = (short)f2u_fast(p);
          }
        ps += __shfl_xor(ps, 16);
        ps += __shfl_xor(ps, 32);
        if (skip) {
          lA += ps;
        } else {
          const float corr = exp2f(mA - mn);
          lA = lA * corr + ps;
          mA = mn;
#pragma unroll
          for (int i = 0; i < 8; ++i) {
            oA[i][0] *= corr; oA[i][1] *= corr; oA[i][2] *= corr; oA[i][3] *= corr;
          }
        }
      }
      // softmax B
      {
        float bm = cB[0][0];
#pragma unroll
        for (int f = 0; f < 4; ++f)
#pragma unroll
          for (int r = 0; r < 4; ++r) bm = fmaxf(bm, cB[f][r]);
        bm = fmaxf(bm, __shfl_xor(bm, 16));
        bm = fmaxf(bm, __shfl_xor(bm, 32));
        const bool skip = __all(bm <= mB + 8.f);
        const float mn = skip ? mB : fmaxf(mB, bm);
        float ps = 0.f;
#pragma unroll
        for (int f = 0; f < 4; ++f)
#pragma unroll
          for (int r = 0; r < 4; ++r) {
            const float p = exp2f(cB[f][r] - mn);
            ps += p;
            if (f < 2) pbB0[(f & 1) * 4 + r] = (short)f2u_fast(p);
            else       pbB1[(f & 1) * 4 + r] = (short)f2u_fast(p);
          }
        ps += __shfl_xor(ps, 16);
        ps += __shfl_xor(ps, 32);
        if (skip) {
          lB += ps;
        } else {
          const float corr = exp2f(mB - mn);
          lB = lB * corr + ps;
          mB = mn;
#pragma unroll
          for (int i = 0; i < 8; ++i) {
            oB[i][0] *= corr; oB[i][1] *= corr; oB[i][2] *= corr; oB[i][3] *= corr;
          }
        }
      }
      // PV: each V read feeds 4 MFMAs (A0/A1/B0/B1 share va0/va1)
      __builtin_amdgcn_s_setprio(1);
#pragma unroll
      for (int db = 0; db < 8; ++db) {
        const bf16x8 va0 = *(const bf16x8*)(Vsc + db * 1024 + rbV + xK[0]);
        const bf16x8 va1 = *(const bf16x8*)(Vsc + db * 1024 + rbV + xK[1]);
        oA[db] = __builtin_amdgcn_mfma_f32_16x16x32_bf16(va0, pbA0, oA[db], 0, 0, 0);
        oA[db] = __builtin_amdgcn_mfma_f32_16x16x32_bf16(va1, pbA1, oA[db], 0, 0, 0);
        oB[db] = __builtin_amdgcn_mfma_f32_16x16x32_bf16(va0, pbB0, oB[db], 0, 0, 0);
        oB[db] = __builtin_amdgcn_mfma_f32_16x16x32_bf16(va1, pbB1, oB[db], 0, 0, 0);
      }
      __builtin_amdgcn_s_setprio(0);
    }
  }

  // epilogue: unnormalized partials + (m,l)
  float* Op = s ? O1 : O0;
  float2* mlp = s ? ml1 : ml0;
  float* prA = Op + (size_t)qrA * (N_HEADS * VD) + h * VD;
  float* prB = Op + (size_t)qrB * (N_HEADS * VD) + h * VD;
#pragma unroll
  for (int db = 0; db < 8; ++db)
#pragma unroll
    for (int r = 0; r < 4; ++r) {
      prA[db * 16 + 4 * g + r] = oA[db][r];
      prB[db * 16 + 4 * g + r] = oB[db][r];
    }
  if (g == 0) {
    mlp[qrA * N_HEADS + h] = make_float2(mA, lA);
    mlp[qrB * N_HEADS + h] = make_float2(mB, lB);
  }
}

// ---------------------------------------------------------------------------
// Merge the two k-splits: out = (wA*O0 + wB*O1) / (wA*l0 + wB*l1), bf16.
// ---------------------------------------------------------------------------
__global__ __launch_bounds__(256) void combine_attn(const float* __restrict__ O0,
                                                    const float* __restrict__ O1,
                                                    const float2* __restrict__ ml0,
                                                    const float2* __restrict__ ml1,
                                                    unsigned short* __restrict__ outb) {
  const int n4 = (S_LEN * N_HEADS * VD) / 4;
  for (int i = blockIdx.x * 256 + threadIdx.x; i < n4; i += gridDim.x * 256) {
    const int e0 = i << 2;
    const int row = e0 >> 11;
    const int h = (e0 >> 7) & 15;
    const float2 a = ml0[row * N_HEADS + h];
    const float2 b = ml1[row * N_HEADS + h];
    const float M = fmaxf(a.x, b.x);
    float wA = exp2f(a.x - M), wB = exp2f(b.x - M);
    const float inv = 1.f / (wA * a.y + wB * b.y);
    wA *= inv; wB *= inv;
    const float4 va = ((const float4*)O0)[i];
    const float4 vb = ((const float4*)O1)[i];
    u16x4 o;
    o[0] = f2u(va.x * wA + vb.x * wB);
    o[1] = f2u(va.y * wA + vb.y * wB);
    o[2] = f2u(va.z * wA + vb.z * wB);
    o[3] = f2u(va.w * wA + vb.w * wB);
    ((u16x4*)outb)[i] = o;
  }
}

// ---------------------------------------------------------------------------
extern "C" void kernel_launch(void* const* d_in, const int* in_sizes, int n_in,
                              void* d_out, int out_size, void* d_ws, size_t ws_size,
                              hipStream_t stream) {
  const float* hidden    = (const float*)d_in[0];
  const int*   pos       = (const int*)d_in[1];
  const float* q_a_w     = (const float*)d_in[2];
  const float* q_a_ln_w  = (const float*)d_in[3];
  const float* q_b_w     = (const float*)d_in[4];
  const float* kv_a_w    = (const float*)d_in[5];
  const float* kv_a_ln_w = (const float*)d_in[6];
  const float* kv_b_w    = (const float*)d_in[7];
  const float* o_w       = (const float*)d_in[8];
  float* out = (float*)d_out;
  (void)in_sizes; (void)n_in; (void)out_size; (void)ws_size;

  // workspace layout (bytes); total ~94 MB (same footprint as round 7)
  char* base = (char*)d_ws;
  unsigned short* qbuf  = (unsigned short*)(base);              // S*3072 bf16  12.58MB
  unsigned short* kvbuf = (unsigned short*)(base + 12582912);   // S*4096 bf16  16.78MB (V half)
  float*          O1p   = (float*)(base + 12582912);            //   overlay (kvbuf dead after build_vt)
  float*          ac    = (float*)(base + 29360128);            // S*2112 f32   17.30MB
  float*          O0p   = (float*)(base + 29360128);            //   overlay (ac dead after rope)
  float2*         ml0   = (float2*)(base + 46661632);           //   overlay on qan (256KB)
  float2*         ml1   = (float2*)(base + 46923776);           //   overlay on qan (+256KB)
  unsigned short* qan   = (unsigned short*)(base + 46661632);   // S*1536 bf16   6.29MB
  unsigned short* ckvn  = (unsigned short*)(base + 52953088);   // S*512 bf16    2.10MB
  unsigned short* Hb    = (unsigned short*)(base + 55050240);   // S*2048 bf16   8.39MB
  unsigned short* Vt    = (unsigned short*)(base + 55050240);   //   overlay (Hb dead after a-proj)
  unsigned short* wbuf  = (unsigned short*)(base + 63438848);   // 4.72M bf16    9.44MB
  unsigned short* attnb = (unsigned short*)(base + 72876032);   // S*2048 bf16   8.39MB
  unsigned short* Kb    = (unsigned short*)(base + 81264640);   // 16*S*192 bf16 12.58MB

  const dim3 b256(256);
  // 192^-0.5 * log2(e): scores come out of QK^T directly in log2 domain
  const float qscale = 0.07216878364870323f * 1.4426950408889634f;

  conv_bf16<<<2048, b256, 0, stream>>>(hidden, Hb, (S_LEN * D_MODEL) / 4, 1.f);

  // fused a-proj: W = [q_a_w ; kv_a_w] (2112 x 2048), C = ac f32 (S x 2112)
  conv2_bf16<<<2048, b256, 0, stream>>>(q_a_w, (Q_LORA * D_MODEL) / 4,
                                        kv_a_w, (AC_W * D_MODEL) / 4, wbuf);
  gemm_mfma<0><<<dim3(17, S_LEN / 128), b256, 0, stream>>>(Hb, wbuf, ac, nullptr, AC_W, D_MODEL);

  rmsnorm_kernel<<<S_LEN, b256, 0, stream>>>(ac, AC_W, q_a_ln_w, qan, Q_LORA, Q_LORA);
  rmsnorm_kernel<<<S_LEN, b256, 0, stream>>>(ac + Q_LORA, AC_W, kv_a_ln_w, ckvn, KV_LORA, KV_LORA);

  // qbuf = qan @ (qscale*q_b_w)^T   (bf16 out)
  conv_bf16<<<2048, b256, 0, stream>>>(q_b_w, wbuf, (N_HEADS * QHD * Q_LORA) / 4, qscale);
  gemm_mfma<1><<<dim3(N_HEADS * QHD / 128, S_LEN / 128), b256, 0, stream>>>(qan, wbuf, qbuf, nullptr, N_HEADS * QHD, Q_LORA);

  // kv_b: k_nope -> Kb directly, values -> kvbuf
  conv_bf16<<<2048, b256, 0, stream>>>(kv_b_w, wbuf, (N_HEADS * 256 * KV_LORA) / 4, 1.f);
  gemm_mfma<2><<<dim3(N_HEADS * 256 / 128, S_LEN / 128), b256, 0, stream>>>(ckvn, wbuf, kvbuf, Kb, N_HEADS * 256, KV_LORA);

  // rope: qbuf q_pe in place; k_pe -> Kb cols 128..192 (all heads)
  rope_kernel<<<S_LEN, 32, 0, stream>>>(qbuf, ac, Kb, pos);

  build_vt<<<dim3(S_LEN / 32, VD / 32, N_HEADS), b256, 0, stream>>>(kvbuf, Vt);

  // split-K flash + combine (O0 over ac, O1 over kvbuf, ml over qan — all dead)
  flash_attn<<<dim3(512), b256, 0, stream>>>(qbuf, Kb, Vt, O0p, O1p, ml0, ml1);
  combine_attn<<<2048, b256, 0, stream>>>(O0p, O1p, ml0, ml1, attnb);

  conv_bf16<<<2048, b256, 0, stream>>>(o_w, wbuf, (D_MODEL * N_HEADS * VD) / 4, 1.f);
  gemm_mfma<0><<<dim3(D_MODEL / 128, S_LEN / 128), b256, 0, stream>>>(attnb, wbuf, out, nullptr, D_MODEL, N_HEADS * VD);
}

// Round 9
// 208.384 us; speedup vs baseline: 1.2768x; 1.2018x over previous
//
#include <hip/hip_runtime.h>
#include <hip/hip_bf16.h>
#include <cmath>

#define S_LEN 2048
#define D_MODEL 2048
#define N_HEADS 16
#define Q_LORA 1536
#define KV_LORA 512
#define NOPE 128
#define ROPE_D 64
#define VD 128
#define QHD 192
#define AC_W 2112  // fused a-proj output width: 1536 q_a + 576 ckv

typedef __attribute__((ext_vector_type(8))) short bf16x8;
typedef __attribute__((ext_vector_type(4))) float f32x4;
typedef __attribute__((ext_vector_type(4))) unsigned short u16x4;

static __device__ __forceinline__ unsigned short f2u(float x) {
  union { float f; unsigned u; } v; v.f = x;
  unsigned r = v.u + 0x7fffu + ((v.u >> 16) & 1u);  // RNE
  return (unsigned short)(r >> 16);
}
static __device__ __forceinline__ unsigned short f2u_fast(float x) {  // round-half-up, x>=0
  union { float f; unsigned u; } v; v.f = x;
  return (unsigned short)((v.u + 0x8000u) >> 16);
}
static __device__ __forceinline__ float u2f(unsigned short x) {
  union { unsigned u; float f; } v; v.u = ((unsigned)x) << 16;
  return v.f;
}

#define AS1 __attribute__((address_space(1)))
#define AS3 __attribute__((address_space(3)))
static __device__ __forceinline__ void gload_lds16(const unsigned short* g, unsigned short* l) {
  __builtin_amdgcn_global_load_lds((const AS1 unsigned int*)g, (AS3 unsigned int*)l, 16, 0, 0);
}

// ---------------------------------------------------------------------------
// f32 -> bf16 convert (optionally scaled). n4 = elements/4.
// ---------------------------------------------------------------------------
__global__ __launch_bounds__(256) void conv_bf16(const float* __restrict__ src,
                                                 unsigned short* __restrict__ dst,
                                                 int n4, float scale) {
  for (int i = blockIdx.x * 256 + threadIdx.x; i < n4; i += gridDim.x * 256) {
    const float4 v = ((const float4*)src)[i];
    u16x4 o;
    o[0] = f2u(v.x * scale); o[1] = f2u(v.y * scale);
    o[2] = f2u(v.z * scale); o[3] = f2u(v.w * scale);
    ((u16x4*)dst)[i] = o;
  }
}

// two-segment variant (fused q_a_w + kv_a_w conversion)
__global__ __launch_bounds__(256) void conv2_bf16(const float* __restrict__ srcA, int n4a,
                                                  const float* __restrict__ srcB, int n4total,
                                                  unsigned short* __restrict__ dst) {
  for (int i = blockIdx.x * 256 + threadIdx.x; i < n4total; i += gridDim.x * 256) {
    const float4 v = (i < n4a) ? ((const float4*)srcA)[i] : ((const float4*)srcB)[i - n4a];
    u16x4 o;
    o[0] = f2u(v.x); o[1] = f2u(v.y); o[2] = f2u(v.z); o[3] = f2u(v.w);
    ((u16x4*)dst)[i] = o;
  }
}

// ---------------------------------------------------------------------------
// bf16 MFMA GEMM: C[M,N] = A[M,K] @ W[N,K]^T. 128x64 tile, BK=64, 4 waves
// (each 64x32 output), double-buffered LDS (48 KB -> up to 3 blocks/CU),
// one barrier per 64-k step. 8-slot rows, slot^(row&7) XOR swizzle (pre-
// swizzled global source + same XOR on ds_read). All N here are multiples
// of 64 -> no guards. MODE 0: f32 C. MODE 1: bf16 C. MODE 2: kv-split.
// ---------------------------------------------------------------------------
template <int MODE>
__global__ __launch_bounds__(256) void gemm_mfma(const unsigned short* __restrict__ A,
                                                 const unsigned short* __restrict__ W,
                                                 void* __restrict__ Cv,
                                                 unsigned short* __restrict__ C2,
                                                 int N, int K) {
  __shared__ unsigned short As[2][8192];  // 128 x 64 bf16
  __shared__ unsigned short Ws[2][4096];  //  64 x 64 bf16
  const int tid = threadIdx.x;
  const int wave = tid >> 6, lane = tid & 63;
  const int col16 = lane & 15, g = lane >> 4;
  const int arow = blockIdx.y * 128, wrow = blockIdx.x * 64;
  const int wm = (wave >> 1) * 64, wn = (wave & 1) * 32;

  const unsigned short* gA[4];
  const unsigned short* gW[2];
  int dA[4], dW[2];
#pragma unroll
  for (int i = 0; i < 4; ++i) {
    const int c = i * 256 + tid;           // 1024 A chunks of 16B
    const int r = c >> 3, sl = c & 7;
    gA[i] = A + (size_t)(arow + r) * K + (sl ^ (r & 7)) * 8;
    dA[i] = c * 8;
  }
#pragma unroll
  for (int i = 0; i < 2; ++i) {
    const int c = i * 256 + tid;           // 512 W chunks of 16B
    const int r = c >> 3, sl = c & 7;
    gW[i] = W + (size_t)(wrow + r) * K + (sl ^ (r & 7)) * 8;
    dW[i] = c * 8;
  }

  f32x4 acc[4][2];
#pragma unroll
  for (int i = 0; i < 4; ++i)
#pragma unroll
    for (int j = 0; j < 2; ++j) acc[i][j] = (f32x4){0.f, 0.f, 0.f, 0.f};

#pragma unroll
  for (int i = 0; i < 4; ++i) gload_lds16(gA[i], &As[0][dA[i]]);
#pragma unroll
  for (int i = 0; i < 2; ++i) gload_lds16(gW[i], &Ws[0][dW[i]]);

  int cur = 0;
  for (int k0 = 0; k0 < K; k0 += 64) {
    __syncthreads();
    if (k0 + 64 < K) {
      const int b = cur ^ 1, kk = k0 + 64;
#pragma unroll
      for (int i = 0; i < 4; ++i) gload_lds16(gA[i] + kk, &As[b][dA[i]]);
#pragma unroll
      for (int i = 0; i < 2; ++i) gload_lds16(gW[i] + kk, &Ws[b][dW[i]]);
    }
#pragma unroll
    for (int kh = 0; kh < 2; ++kh) {
      bf16x8 af[4], bfr[2];
#pragma unroll
      for (int i = 0; i < 4; ++i) {
        const int row = wm + i * 16 + col16;
        af[i] = *(const bf16x8*)(&As[cur][row * 64 + (((kh * 4 + g) ^ (row & 7)) * 8)]);
      }
#pragma unroll
      for (int j = 0; j < 2; ++j) {
        const int row = wn + j * 16 + col16;
        bfr[j] = *(const bf16x8*)(&Ws[cur][row * 64 + (((kh * 4 + g) ^ (row & 7)) * 8)]);
      }
#pragma unroll
      for (int i = 0; i < 4; ++i)
#pragma unroll
        for (int j = 0; j < 2; ++j)
          acc[i][j] = __builtin_amdgcn_mfma_f32_16x16x32_bf16(af[i], bfr[j], acc[i][j], 0, 0, 0);
    }
    cur ^= 1;
  }

#pragma unroll
  for (int i = 0; i < 4; ++i)
#pragma unroll
    for (int j = 0; j < 2; ++j) {
      const int col = wrow + wn + j * 16 + col16;
      const int row0 = arow + wm + i * 16 + g * 4;
#pragma unroll
      for (int r = 0; r < 4; ++r) {
        if constexpr (MODE == 0)
          ((float*)Cv)[(size_t)(row0 + r) * N + col] = acc[i][j][r];
        else if constexpr (MODE == 1)
          ((unsigned short*)Cv)[(size_t)(row0 + r) * N + col] = f2u(acc[i][j][r]);
        else {
          const int hh = col >> 8, d = col & 255;
          if (d < NOPE)
            C2[((size_t)hh * S_LEN + row0 + r) * QHD + d] = f2u(acc[i][j][r]);
          else
            ((unsigned short*)Cv)[(size_t)(row0 + r) * (N_HEADS * 256) + col] = f2u(acc[i][j][r]);
        }
      }
    }
}

// ---------------------------------------------------------------------------
// RMSNorm over last dim, f32 in -> bf16 out.
// ---------------------------------------------------------------------------
__global__ __launch_bounds__(256) void rmsnorm_kernel(const float* __restrict__ src, int src_ld,
                                                      const float* __restrict__ w,
                                                      unsigned short* __restrict__ dst, int dst_ld,
                                                      int dim) {
  const int row = blockIdx.x;
  const float* x = src + (size_t)row * src_ld;
  float ss = 0.f;
  for (int i = threadIdx.x; i < dim; i += 256) {
    float v = x[i];
    ss += v * v;
  }
#pragma unroll
  for (int off = 32; off; off >>= 1) ss += __shfl_xor(ss, off);
  __shared__ float red[4];
  const int wv = threadIdx.x >> 6, ln = threadIdx.x & 63;
  if (ln == 0) red[wv] = ss;
  __syncthreads();
  const float tot = red[0] + red[1] + red[2] + red[3];
  const float scale = rsqrtf(tot / (float)dim + 1e-6f);
  for (int i = threadIdx.x; i < dim; i += 256) {
    dst[(size_t)row * dst_ld + i] = f2u(w[i] * (x[i] * scale));
  }
}

// ---------------------------------------------------------------------------
// RoPE: q_pe slices of bf16 qbuf in place; k_pe -> broadcast into Kb.
// ---------------------------------------------------------------------------
__global__ void rope_kernel(unsigned short* __restrict__ q, const float* __restrict__ ac,
                            unsigned short* __restrict__ Kb, const int* __restrict__ pos_ids) {
  const int s = blockIdx.x;
  const int j = threadIdx.x;  // 0..31
  const float t = (float)pos_ids[s];
  const float invf = powf(50000.0f, -(float)(2 * j) / 64.0f);
  const float ang = t * invf;
  const float c = cosf(ang), sn = sinf(ang);
  for (int h = 0; h < N_HEADS; ++h) {
    unsigned short* base = q + (size_t)s * (N_HEADS * QHD) + h * QHD + NOPE;
    const float x0 = u2f(base[2 * j]), x1 = u2f(base[2 * j + 1]);
    __syncthreads();
    base[j] = f2u(x0 * c - x1 * sn);
    base[32 + j] = f2u(x1 * c + x0 * sn);
    __syncthreads();
  }
  const float* kb = ac + (size_t)s * AC_W + 2048;
  const unsigned short r0 = f2u(kb[2 * j] * c - kb[2 * j + 1] * sn);
  const unsigned short r1 = f2u(kb[2 * j + 1] * c + kb[2 * j] * sn);
#pragma unroll
  for (int h = 0; h < N_HEADS; ++h) {
    unsigned short* kd = Kb + ((size_t)h * S_LEN + s) * QHD + NOPE;
    kd[j] = r0;
    kd[32 + j] = r1;
  }
}

// ---------------------------------------------------------------------------
// V transpose + PERMUTED column order (PV fragment order), unchanged.
// ---------------------------------------------------------------------------
__global__ __launch_bounds__(256) void build_vt(const unsigned short* __restrict__ kv,
                                                unsigned short* __restrict__ Vt) {
  __shared__ unsigned short t[32][33];
  const int s0 = blockIdx.x * 32, d0 = blockIdx.y * 32, h = blockIdx.z;
  const int tx = threadIdx.x & 31, ty = threadIdx.x >> 5;
#pragma unroll
  for (int i = 0; i < 4; ++i) {
    const int s = s0 + ty + i * 8;
    t[ty + i * 8][tx] = kv[(size_t)s * (N_HEADS * 256) + h * 256 + NOPE + d0 + tx];
  }
  __syncthreads();
  const int p = ((tx & 15) >> 2) * 8 + ((tx >> 4) & 1) * 4 + (tx & 3);
#pragma unroll
  for (int i = 0; i < 4; ++i) {
    const int d = d0 + ty + i * 8;
    Vt[((size_t)h * VD + d) * S_LEN + s0 + p] = t[tx][ty + i * 8];
  }
}

// ---------------------------------------------------------------------------
// Split-K MFMA flash attention, occupancy-first: 32-k double-buffered tiles
// (40 KB LDS), 4 waves x 16 q = 64 rows/block, grid 1024 (32 qblocks x 16
// heads x 2 splits) -> 4 blocks/CU = 4 waves/SIMD (vs 2 in rounds 5-8).
// Split s takes k-tiles j == s (mod 2): both splits get exactly t+1 tiles.
// Co-resident blocks {z, z+8, z+16, z+24} sum to 66 intervals (balanced).
// Writes unnormalized f32 partials + (m,l); combine_attn merges.
// ---------------------------------------------------------------------------
__global__ __launch_bounds__(256, 4) void flash_attn(const unsigned short* __restrict__ Q,   // (S,3072) pre-scaled
                                                     const unsigned short* __restrict__ Kb,  // (H,S,192)
                                                     const unsigned short* __restrict__ Vt,  // (H,128,S) permuted
                                                     float* __restrict__ O0,
                                                     float* __restrict__ O1,
                                                     float2* __restrict__ ml0,
                                                     float2* __restrict__ ml1) {
  __shared__ unsigned short Ks[2][32 * QHD];   // 2 x 12 KB
  __shared__ unsigned short Vs[2][VD * 32];    // 2 x  8 KB
  const int tid = threadIdx.x;
  const int wave = tid >> 6, lane = tid & 63;
  const int g = lane >> 4, col = lane & 15;
  const int lin = (int)blockIdx.x;                    // 0..1023
  const int h = ((lin & 7) << 1) | ((lin >> 3) & 1);  // XCD owns a head pair
  const int s = (lin >> 4) & 1;                       // k-split
  const int z = lin >> 5;                             // 0..31
  int t;                                              // balanced qblock mapping
  if (z < 8) t = 31 - z;
  else if (z < 16) t = z - 8;
  else if (z < 24) t = 39 - z;
  else t = z - 16;
  const int qw = t * 64 + wave * 16;
  const int qr = qw + col;

  bf16x8 qf[6];
  {
    const unsigned short* qrow = Q + (size_t)qr * (N_HEADS * QHD) + h * QHD + g * 8;
#pragma unroll
    for (int i = 0; i < 6; ++i) qf[i] = *(const bf16x8*)(qrow + i * 32);
  }

  const unsigned short* KbH = Kb + (size_t)h * S_LEN * QHD;
  const unsigned short* VtH = Vt + (size_t)h * VD * S_LEN;

  // staging source offsets (pre-swizzled slots; fixed across tiles)
  int eK[3], eV[2];
#pragma unroll
  for (int i = 0; i < 3; ++i) {                 // 768 K chunks of 16B
    const int c = i * 256 + tid;
    const int r = c / 24, sl = c - r * 24;
    eK[i] = r * QHD + (((sl & 24) | ((sl & 7) ^ (r & 7)))) * 8;
  }
#pragma unroll
  for (int i = 0; i < 2; ++i) {                 // 512 V chunks of 16B
    const int c = i * 256 + tid;
    const int d = c >> 2, sl = c & 3;
    eV[i] = d * S_LEN + ((sl ^ (d & 3))) * 8;
  }

  f32x4 o[8];
#pragma unroll
  for (int i = 0; i < 8; ++i) o[i] = (f32x4){0.f, 0.f, 0.f, 0.f};
  float m = -1e30f, l = 0.f;

  const int nT = t + 1;  // tiles j = 2*it + s

  // prologue: stage tile j=s into buffer 0
  {
    const unsigned short* kp = KbH + (size_t)s * 32 * QHD;
    const unsigned short* vp = VtH + s * 32;
#pragma unroll
    for (int i = 0; i < 3; ++i) gload_lds16(kp + eK[i], &Ks[0][(i * 256 + tid) * 8]);
#pragma unroll
    for (int i = 0; i < 2; ++i) gload_lds16(vp + eV[i], &Vs[0][(i * 256 + tid) * 8]);
  }

  int xK[6];
#pragma unroll
  for (int i = 0; i < 6; ++i) xK[i] = ((4 * i + g) ^ (col & 7)) * 8;
  const int rbK = col * QHD;
  const int xV = (g ^ (col & 3)) * 8;
  const int rbV = col * 32;

  for (int it = 0; it < nT; ++it) {
    __syncthreads();
    if (it + 1 < nT) {
      const int jn = 2 * (it + 1) + s;
      const unsigned short* kp = KbH + (size_t)jn * 32 * QHD;
      const unsigned short* vp = VtH + jn * 32;
      const int b = (it + 1) & 1;
#pragma unroll
      for (int i = 0; i < 3; ++i) gload_lds16(kp + eK[i], &Ks[b][(i * 256 + tid) * 8]);
#pragma unroll
      for (int i = 0; i < 2; ++i) gload_lds16(vp + eV[i], &Vs[b][(i * 256 + tid) * 8]);
    }
    const int k0 = 32 * (2 * it + s);
    if (k0 <= qw + 15) {
      const unsigned short* Ksc = Ks[it & 1];
      const unsigned short* Vsc = Vs[it & 1];

      f32x4 c0 = (f32x4){0.f, 0.f, 0.f, 0.f}, c1 = (f32x4){0.f, 0.f, 0.f, 0.f};
      __builtin_amdgcn_s_setprio(1);
#pragma unroll
      for (int dt = 0; dt < 6; ++dt) {
        const bf16x8 a0 = *(const bf16x8*)(Ksc + rbK + xK[dt]);
        const bf16x8 a1 = *(const bf16x8*)(Ksc + rbK + 16 * QHD + xK[dt]);
        c0 = __builtin_amdgcn_mfma_f32_16x16x32_bf16(a0, qf[dt], c0, 0, 0, 0);
        c1 = __builtin_amdgcn_mfma_f32_16x16x32_bf16(a1, qf[dt], c1, 0, 0, 0);
      }
      __builtin_amdgcn_s_setprio(0);

      // causal mask only on diagonal tiles (k = k0 + 16f + 4g + r)
      if (k0 + 31 > qw) {
#pragma unroll
        for (int r = 0; r < 4; ++r) {
          const int kk = k0 + 4 * g + r;
          if (kk > qr) c0[r] = -1e30f;
          if (kk + 16 > qr) c1[r] = -1e30f;
        }
      }
      float bm = fmaxf(fmaxf(fmaxf(c0[0], c0[1]), fmaxf(c0[2], c0[3])),
                       fmaxf(fmaxf(c1[0], c1[1]), fmaxf(c1[2], c1[3])));
      bm = fmaxf(bm, __shfl_xor(bm, 16));
      bm = fmaxf(bm, __shfl_xor(bm, 32));
      const bool skip = __all(bm <= m + 8.f);   // defer-max: p bounded by 2^8
      const float mn = skip ? m : fmaxf(m, bm);
      float ps = 0.f;
      bf16x8 pb;
#pragma unroll
      for (int r = 0; r < 4; ++r) {
        const float p0 = exp2f(c0[r] - mn);
        const float p1 = exp2f(c1[r] - mn);
        ps += p0 + p1;
        pb[r] = (short)f2u_fast(p0);
        pb[4 + r] = (short)f2u_fast(p1);
      }
      ps += __shfl_xor(ps, 16);
      ps += __shfl_xor(ps, 32);
      if (skip) {
        l += ps;
      } else {
        const float corr = exp2f(m - mn);
        l = l * corr + ps;
        m = mn;
#pragma unroll
        for (int i = 0; i < 8; ++i) {
          o[i][0] *= corr; o[i][1] *= corr; o[i][2] *= corr; o[i][3] *= corr;
        }
      }
      __builtin_amdgcn_s_setprio(1);
#pragma unroll
      for (int db = 0; db < 8; ++db) {
        const bf16x8 va = *(const bf16x8*)(Vsc + db * 512 + rbV + xV);
        o[db] = __builtin_amdgcn_mfma_f32_16x16x32_bf16(va, pb, o[db], 0, 0, 0);
      }
      __builtin_amdgcn_s_setprio(0);
    }
  }

  // epilogue: unnormalized partials + (m,l)
  float* Op = s ? O1 : O0;
  float2* mlp = s ? ml1 : ml0;
  float* pr = Op + (size_t)qr * (N_HEADS * VD) + h * VD;
#pragma unroll
  for (int db = 0; db < 8; ++db)
#pragma unroll
    for (int r = 0; r < 4; ++r)
      pr[db * 16 + 4 * g + r] = o[db][r];
  if (g == 0) mlp[qr * N_HEADS + h] = make_float2(m, l);
}

// ---------------------------------------------------------------------------
// Merge the two k-splits: out = (wA*O0 + wB*O1) / (wA*l0 + wB*l1), bf16.
// ---------------------------------------------------------------------------
__global__ __launch_bounds__(256) void combine_attn(const float* __restrict__ O0,
                                                    const float* __restrict__ O1,
                                                    const float2* __restrict__ ml0,
                                                    const float2* __restrict__ ml1,
                                                    unsigned short* __restrict__ outb) {
  const int n4 = (S_LEN * N_HEADS * VD) / 4;
  for (int i = blockIdx.x * 256 + threadIdx.x; i < n4; i += gridDim.x * 256) {
    const int e0 = i << 2;
    const int row = e0 >> 11;
    const int h = (e0 >> 7) & 15;
    const float2 a = ml0[row * N_HEADS + h];
    const float2 b = ml1[row * N_HEADS + h];
    const float M = fmaxf(a.x, b.x);
    float wA = exp2f(a.x - M), wB = exp2f(b.x - M);
    const float inv = 1.f / (wA * a.y + wB * b.y);
    wA *= inv; wB *= inv;
    const float4 va = ((const float4*)O0)[i];
    const float4 vb = ((const float4*)O1)[i];
    u16x4 o;
    o[0] = f2u(va.x * wA + vb.x * wB);
    o[1] = f2u(va.y * wA + vb.y * wB);
    o[2] = f2u(va.z * wA + vb.z * wB);
    o[3] = f2u(va.w * wA + vb.w * wB);
    ((u16x4*)outb)[i] = o;
  }
}

// ---------------------------------------------------------------------------
extern "C" void kernel_launch(void* const* d_in, const int* in_sizes, int n_in,
                              void* d_out, int out_size, void* d_ws, size_t ws_size,
                              hipStream_t stream) {
  const float* hidden    = (const float*)d_in[0];
  const int*   pos       = (const int*)d_in[1];
  const float* q_a_w     = (const float*)d_in[2];
  const float* q_a_ln_w  = (const float*)d_in[3];
  const float* q_b_w     = (const float*)d_in[4];
  const float* kv_a_w    = (const float*)d_in[5];
  const float* kv_a_ln_w = (const float*)d_in[6];
  const float* kv_b_w    = (const float*)d_in[7];
  const float* o_w       = (const float*)d_in[8];
  float* out = (float*)d_out;
  (void)in_sizes; (void)n_in; (void)out_size; (void)ws_size;

  // workspace layout (bytes); total ~94 MB
  char* base = (char*)d_ws;
  unsigned short* qbuf  = (unsigned short*)(base);              // S*3072 bf16  12.58MB
  unsigned short* kvbuf = (unsigned short*)(base + 12582912);   // S*4096 bf16  16.78MB (V half)
  float*          O1p   = (float*)(base + 12582912);            //   overlay (kvbuf dead after build_vt)
  float*          ac    = (float*)(base + 29360128);            // S*2112 f32   17.30MB
  float*          O0p   = (float*)(base + 29360128);            //   overlay (ac dead after rope)
  float2*         ml0   = (float2*)(base + 46661632);           //   overlay on qan (256KB)
  float2*         ml1   = (float2*)(base + 46923776);           //   overlay on qan (+256KB)
  unsigned short* qan   = (unsigned short*)(base + 46661632);   // S*1536 bf16   6.29MB
  unsigned short* ckvn  = (unsigned short*)(base + 52953088);   // S*512 bf16    2.10MB
  unsigned short* Hb    = (unsigned short*)(base + 55050240);   // S*2048 bf16   8.39MB
  unsigned short* Vt    = (unsigned short*)(base + 55050240);   //   overlay (Hb dead after a-proj)
  unsigned short* wbuf  = (unsigned short*)(base + 63438848);   // 4.72M bf16    9.44MB
  unsigned short* attnb = (unsigned short*)(base + 72876032);   // S*2048 bf16   8.39MB
  unsigned short* Kb    = (unsigned short*)(base + 81264640);   // 16*S*192 bf16 12.58MB

  const dim3 b256(256);
  // 192^-0.5 * log2(e): scores come out of QK^T directly in log2 domain
  const float qscale = 0.07216878364870323f * 1.4426950408889634f;

  conv_bf16<<<2048, b256, 0, stream>>>(hidden, Hb, (S_LEN * D_MODEL) / 4, 1.f);

  // fused a-proj: W = [q_a_w ; kv_a_w] (2112 x 2048), C = ac f32 (S x 2112)
  conv2_bf16<<<2048, b256, 0, stream>>>(q_a_w, (Q_LORA * D_MODEL) / 4,
                                        kv_a_w, (AC_W * D_MODEL) / 4, wbuf);
  gemm_mfma<0><<<dim3(AC_W / 64, S_LEN / 128), b256, 0, stream>>>(Hb, wbuf, ac, nullptr, AC_W, D_MODEL);

  rmsnorm_kernel<<<S_LEN, b256, 0, stream>>>(ac, AC_W, q_a_ln_w, qan, Q_LORA, Q_LORA);
  rmsnorm_kernel<<<S_LEN, b256, 0, stream>>>(ac + Q_LORA, AC_W, kv_a_ln_w, ckvn, KV_LORA, KV_LORA);

  // qbuf = qan @ (qscale*q_b_w)^T   (bf16 out)
  conv_bf16<<<2048, b256, 0, stream>>>(q_b_w, wbuf, (N_HEADS * QHD * Q_LORA) / 4, qscale);
  gemm_mfma<1><<<dim3(N_HEADS * QHD / 64, S_LEN / 128), b256, 0, stream>>>(qan, wbuf, qbuf, nullptr, N_HEADS * QHD, Q_LORA);

  // kv_b: k_nope -> Kb directly, values -> kvbuf
  conv_bf16<<<2048, b256, 0, stream>>>(kv_b_w, wbuf, (N_HEADS * 256 * KV_LORA) / 4, 1.f);
  gemm_mfma<2><<<dim3(N_HEADS * 256 / 64, S_LEN / 128), b256, 0, stream>>>(ckvn, wbuf, kvbuf, Kb, N_HEADS * 256, KV_LORA);

  // rope: qbuf q_pe in place; k_pe -> Kb cols 128..192 (all heads)
  rope_kernel<<<S_LEN, 32, 0, stream>>>(qbuf, ac, Kb, pos);

  build_vt<<<dim3(S_LEN / 32, VD / 32, N_HEADS), b256, 0, stream>>>(kvbuf, Vt);

  // split-K flash + combine (O0 over ac, O1 over kvbuf, ml over qan — all dead)
  flash_attn<<<dim3(1024), b256, 0, stream>>>(qbuf, Kb, Vt, O0p, O1p, ml0, ml1);
  combine_attn<<<2048, b256, 0, stream>>>(O0p, O1p, ml0, ml1, attnb);

  conv_bf16<<<2048, b256, 0, stream>>>(o_w, wbuf, (D_MODEL * N_HEADS * VD) / 4, 1.f);
  gemm_mfma<0><<<dim3(D_MODEL / 64, S_LEN / 128), b256, 0, stream>>>(attnb, wbuf, out, nullptr, D_MODEL, N_HEADS * VD);
}